// Round 10
// baseline (1677.084 us; speedup 1.0000x reference)
//
#include <hip/hip_runtime.h>
#include <hip/hip_fp16.h>

// LSTM T=512 B=64 D=256 H=256, fp32 in/out.
//
// Phase 0: X->f16; Wxt [4H][K] for the gx GEMM; Wh2 = Wh packed in MFMA
//          B-fragment order, unit-major columns (c = 4u+g).
// Phase 1: gx = X @ Wx + b via MFMA (M=32768, K=256, N=1024) -> ws f16.
// Phase 2: recurrence, 1 CU per batch, 256 threads (4 waves, 1 wave/SIMD ->
//          512 unified regs/wave). gates = h @ Wh via mfma_f32_16x16x32_f16,
//          A = h broadcast to all 16 rows (row 0 of C is the result).
//          Wave owns 256 cols = 16 N-tiles x 8 K-tiles: 10 nt in regs
//          (320 regs, AGPR-OK for MFMA B), 4 nt in LDS (128 KB), 2 nt
//          streamed from L2 each step (same 512KB for all CUs -> L2-hit).
//          Epilogue: act[c]=gate f32 in LDS; thread u reads float4 act[4u..],
//          does s/h update locally. f32 accumulation.

#define T_STEPS 512
#define BATCH   64
#define HID     256
#define G4      1024
#define GM      (T_STEPS * BATCH)     // 32768

typedef _Float16 half2_t __attribute__((ext_vector_type(2)));
typedef _Float16 f16x8   __attribute__((ext_vector_type(8)));
typedef float    f32x4   __attribute__((ext_vector_type(4)));

// ws element offsets (f16 elements)
#define XH_OFF  0u          // [32768][256]  f16
#define WXT_OFF 8388608u    // [1024][256]   f16
#define WH2_OFF 8650752u    // [512 blocks][512] f16 (frag-ordered Wh)
#define GX_OFF  8912896u    // [32768][1024] f16

__device__ __forceinline__ float fast_sigmoid(float x) {
    return 1.0f / (1.0f + __expf(-x));
}
__device__ __forceinline__ float fast_tanh(float x) {
    return 2.0f / (1.0f + __expf(-2.0f * x)) - 1.0f;
}

// ---------------- Phase 0a: X f32 -> f16 ----------------
__global__ __launch_bounds__(256) void k_prep_x(const float* __restrict__ X,
                                                _Float16* __restrict__ Xh) {
    const int i = blockIdx.x * 256 + threadIdx.x;
    float4 v = ((const float4*)X)[i];
    half2_t a; a.x = (_Float16)v.x; a.y = (_Float16)v.y;
    half2_t b; b.x = (_Float16)v.z; b.y = (_Float16)v.w;
    ((half2_t*)Xh)[2 * i]     = a;
    ((half2_t*)Xh)[2 * i + 1] = b;
}

// ---------------- Phase 0b: Wxt [4H][K] (gate-major cols) ----------------
__global__ __launch_bounds__(256) void k_prep_w(
    const float* __restrict__ Wax, const float* __restrict__ Wix,
    const float* __restrict__ Wfx, const float* __restrict__ Wox,
    _Float16* __restrict__ Wxt)
{
    const int id = blockIdx.x * 256 + threadIdx.x;   // [0, 262144)
    const int k  = id >> 10;
    const int c  = id & 1023;
    const int g  = c >> 8;
    const int j  = c & 255;
    const float* src = (g == 0) ? Wax : (g == 1) ? Wix : (g == 2) ? Wfx : Wox;
    Wxt[c * 256 + k] = (_Float16)src[k * 256 + j];
}

// ---------------- Phase 0c: Wh2 fragment-ordered (unit-major cols) --------
// Block b_ = gnt*8 + kt (gnt in [0,64), kt in [0,8)); lane l holds 8 f16:
// col c = gnt*16 + (l&15); unit u=c>>2, gate g=c&3; k = kt*32+(l>>4)*8+e.
__global__ __launch_bounds__(256) void k_prep_wfrag(
    const float* __restrict__ Wah, const float* __restrict__ Wih,
    const float* __restrict__ Wfh, const float* __restrict__ Woh,
    _Float16* __restrict__ Wh2)
{
    const int id  = blockIdx.x * 256 + threadIdx.x;   // [0, 32768)
    const int b_  = id >> 6;
    const int l   = id & 63;
    const int gnt = b_ >> 3;
    const int kt  = b_ & 7;
    const int c   = gnt * 16 + (l & 15);
    const int u   = c >> 2;
    const int g   = c & 3;
    const int k0  = kt * 32 + (l >> 4) * 8;
    const float* W = (g == 0) ? Wah : (g == 1) ? Wih : (g == 2) ? Wfh : Woh;
    f16x8 v;
#pragma unroll
    for (int e = 0; e < 8; ++e)
        v[e] = (_Float16)W[(size_t)(k0 + e) * 256 + u];
    *(f16x8*)(Wh2 + (size_t)b_ * 512 + l * 8) = v;
}

// ---------------- Phase 1: gx = Xh @ Wxt^T + b ----------------
__global__ __launch_bounds__(256) void k_gemm(const _Float16* __restrict__ Xh,
                                              const _Float16* __restrict__ Wxt,
                                              const float* __restrict__ ba,
                                              const float* __restrict__ bi,
                                              const float* __restrict__ bf_,
                                              const float* __restrict__ bo,
                                              _Float16* __restrict__ gx)
{
    const int lane = threadIdx.x & 63, wave = threadIdx.x >> 6;
    const int rowbase = blockIdx.x * 128 + wave * 32;
    const int colbase = blockIdx.y * 64;
    const int r15 = lane & 15, kg = lane >> 4;

    f32x4 acc[2][4] = {};
    const _Float16* ap0 = Xh  + (size_t)(rowbase + r15) * 256 + kg * 8;
    const _Float16* ap1 = ap0 + 16 * 256;
    const _Float16* bp  = Wxt + (size_t)(colbase + r15) * 256 + kg * 8;

#pragma unroll
    for (int ks = 0; ks < 8; ++ks) {
        f16x8 a0 = *(const f16x8*)(ap0 + ks * 32);
        f16x8 a1 = *(const f16x8*)(ap1 + ks * 32);
        f16x8 b0 = *(const f16x8*)(bp  + ks * 32);
        f16x8 b1 = *(const f16x8*)(bp  + 16 * 256 + ks * 32);
        f16x8 b2 = *(const f16x8*)(bp  + 32 * 256 + ks * 32);
        f16x8 b3 = *(const f16x8*)(bp  + 48 * 256 + ks * 32);
        acc[0][0] = __builtin_amdgcn_mfma_f32_16x16x32_f16(a0, b0, acc[0][0], 0, 0, 0);
        acc[0][1] = __builtin_amdgcn_mfma_f32_16x16x32_f16(a0, b1, acc[0][1], 0, 0, 0);
        acc[0][2] = __builtin_amdgcn_mfma_f32_16x16x32_f16(a0, b2, acc[0][2], 0, 0, 0);
        acc[0][3] = __builtin_amdgcn_mfma_f32_16x16x32_f16(a0, b3, acc[0][3], 0, 0, 0);
        acc[1][0] = __builtin_amdgcn_mfma_f32_16x16x32_f16(a1, b0, acc[1][0], 0, 0, 0);
        acc[1][1] = __builtin_amdgcn_mfma_f32_16x16x32_f16(a1, b1, acc[1][1], 0, 0, 0);
        acc[1][2] = __builtin_amdgcn_mfma_f32_16x16x32_f16(a1, b2, acc[1][2], 0, 0, 0);
        acc[1][3] = __builtin_amdgcn_mfma_f32_16x16x32_f16(a1, b3, acc[1][3], 0, 0, 0);
    }
    float bias_n[4];
#pragma unroll
    for (int nt = 0; nt < 4; ++nt) {
        int col = colbase + nt * 16 + r15;
        bias_n[nt] = (col < 256) ? ba[col]
                   : (col < 512) ? bi[col - 256]
                   : (col < 768) ? bf_[col - 512]
                                 : bo[col - 768];
    }
#pragma unroll
    for (int mt = 0; mt < 2; ++mt)
#pragma unroll
        for (int nt = 0; nt < 4; ++nt)
#pragma unroll
            for (int r = 0; r < 4; ++r) {
                int row = rowbase + mt * 16 + kg * 4 + r;
                int col = colbase + nt * 16 + r15;
                gx[(size_t)row * G4 + col] = (_Float16)(acc[mt][nt][r] + bias_n[nt]);
            }
}

// ---------------- Phase 2: MFMA recurrence ----------------

#define MFMA16(a, bfr, acc) __builtin_amdgcn_mfma_f32_16x16x32_f16(a, bfr, acc, 0, 0, 0)

#define LDW(n, k)  (*(const f16x8*)(Wb  + ((n)  * 8 + (k)) * 512))
#define LDWS(n, k) (*(const f16x8*)(Wbs + ((n)  * 8 + (k)) * 512))
#define LDL(n, k)  (*(const f16x8*)(wlw + (((n) - 10) * 8 + (k)) * 512))

#define DECLNT(n)                                                              \
    f16x8 wr##n##_0 = LDW(n, 0), wr##n##_1 = LDW(n, 1),                        \
          wr##n##_2 = LDW(n, 2), wr##n##_3 = LDW(n, 3),                        \
          wr##n##_4 = LDW(n, 4), wr##n##_5 = LDW(n, 5),                        \
          wr##n##_6 = LDW(n, 6), wr##n##_7 = LDW(n, 7);

#define NT_BODY(B0, B1, B2, B3, B4, B5, B6, B7, n)                             \
    {                                                                          \
        f32x4 acc = {0.f, 0.f, 0.f, 0.f};                                      \
        acc = MFMA16(a0, B0, acc); acc = MFMA16(a1, B1, acc);                  \
        acc = MFMA16(a2, B2, acc); acc = MFMA16(a3, B3, acc);                  \
        acc = MFMA16(a4, B4, acc); acc = MFMA16(a5, B5, acc);                  \
        acc = MFMA16(a6, B6, acc); acc = MFMA16(a7, B7, acc);                  \
        if (lane < 16) act[w * 256 + (n) * 16 + lane] = acc[0];                \
    }

#define NT_REG(n) NT_BODY(wr##n##_0, wr##n##_1, wr##n##_2, wr##n##_3,          \
                          wr##n##_4, wr##n##_5, wr##n##_6, wr##n##_7, n)

#define NT_LDS(n)                                                              \
    {                                                                          \
        f16x8 b0 = LDL(n, 0), b1 = LDL(n, 1), b2 = LDL(n, 2), b3 = LDL(n, 3); \
        f16x8 b4 = LDL(n, 4), b5 = LDL(n, 5), b6 = LDL(n, 6), b7 = LDL(n, 7); \
        NT_BODY(b0, b1, b2, b3, b4, b5, b6, b7, n)                             \
    }

__global__ void __launch_bounds__(256, 1)
__attribute__((amdgpu_waves_per_eu(1, 1)))
k_recur(const _Float16* __restrict__ Wh2, const _Float16* __restrict__ gx,
        float* __restrict__ out)
{
    const int b    = blockIdx.x;
    const int tid  = threadIdx.x;      // 0..255
    const int lane = tid & 63;
    const int w    = tid >> 6;         // wave: cols [256w, 256w+256)

    __shared__ __align__(16) _Float16 wl[4 * 4 * 8 * 512];  // 128 KB (nt 10..13)
    __shared__ __align__(16) float    act[1024];            // 4 KB
    __shared__ __align__(16) _Float16 hbuf[256];            // 512 B

    // wave's fragment base: global ntile = w*16 + n
    const _Float16* Wb = Wh2 + ((size_t)w * 16 * 8) * 512 + lane * 8;

    // ---- persistent register fragments: nt 0..9 (320 regs, AGPR-friendly) ----
    DECLNT(0) DECLNT(1) DECLNT(2) DECLNT(3) DECLNT(4)
    DECLNT(5) DECLNT(6) DECLNT(7) DECLNT(8) DECLNT(9)

    // ---- LDS fragments: nt 10..13 ----
    _Float16* wlw = wl + (size_t)(w * 32) * 512 + lane * 8;
#pragma unroll
    for (int n = 0; n < 4; ++n)
#pragma unroll
        for (int k = 0; k < 8; ++k)
            *(f16x8*)(wlw + (n * 8 + k) * 512) = LDW(10 + n, k);

    hbuf[tid] = (_Float16)0.0f;
    float s = 0.0f;
    _Float16 gc0 = gx[(size_t)b * G4 + tid];
    _Float16 gc1 = gx[(size_t)b * G4 + 256 + tid];
    _Float16 gc2 = gx[(size_t)b * G4 + 512 + tid];
    _Float16 gc3 = gx[(size_t)b * G4 + 768 + tid];
    __syncthreads();

#pragma unroll 1
    for (int t = 0; t < T_STEPS; ++t) {
        // A-fragments: h broadcast to all 16 rows (lane>>4 picks k-subchunk)
        const _Float16* hap = hbuf + ((lane >> 4) & 3) * 8;
        f16x8 a0 = *(const f16x8*)(hap + 0 * 32);
        f16x8 a1 = *(const f16x8*)(hap + 1 * 32);
        f16x8 a2 = *(const f16x8*)(hap + 2 * 32);
        f16x8 a3 = *(const f16x8*)(hap + 3 * 32);
        f16x8 a4 = *(const f16x8*)(hap + 4 * 32);
        f16x8 a5 = *(const f16x8*)(hap + 5 * 32);
        f16x8 a6 = *(const f16x8*)(hap + 6 * 32);
        f16x8 a7 = *(const f16x8*)(hap + 7 * 32);

        // L2-streamed fragments: nt 14, 15 (anti-LICM via opaque pointer)
        const _Float16* Wbs = Wb;
        asm volatile("" : "+v"(Wbs));
        f16x8 s14_0 = LDWS(14, 0), s14_1 = LDWS(14, 1), s14_2 = LDWS(14, 2),
              s14_3 = LDWS(14, 3), s14_4 = LDWS(14, 4), s14_5 = LDWS(14, 5),
              s14_6 = LDWS(14, 6), s14_7 = LDWS(14, 7);

        NT_REG(0) NT_REG(1) NT_REG(2) NT_REG(3) NT_REG(4)

        f16x8 s15_0 = LDWS(15, 0), s15_1 = LDWS(15, 1), s15_2 = LDWS(15, 2),
              s15_3 = LDWS(15, 3), s15_4 = LDWS(15, 4), s15_5 = LDWS(15, 5),
              s15_6 = LDWS(15, 6), s15_7 = LDWS(15, 7);

        NT_REG(5) NT_REG(6) NT_REG(7) NT_REG(8) NT_REG(9)
        NT_LDS(10) NT_LDS(11) NT_LDS(12) NT_LDS(13)
        NT_BODY(s14_0, s14_1, s14_2, s14_3, s14_4, s14_5, s14_6, s14_7, 14)
        NT_BODY(s15_0, s15_1, s15_2, s15_3, s15_4, s15_5, s15_6, s15_7, 15)

        __syncthreads();   // act complete; all A-reads of hbuf done

        // ---- epilogue: thread u = tid owns unit u; act cols 4u..4u+3 ----
        {
            _Float16 gn0 = (_Float16)0.0f, gn1 = (_Float16)0.0f;
            _Float16 gn2 = (_Float16)0.0f, gn3 = (_Float16)0.0f;
            if (t + 1 < T_STEPS) {
                const size_t m = ((size_t)(t + 1) * BATCH + b) * G4;
                gn0 = gx[m + tid];       gn1 = gx[m + 256 + tid];
                gn2 = gx[m + 512 + tid]; gn3 = gx[m + 768 + tid];
            }
            float4 g4 = ((const float4*)act)[tid];   // a,i,f,o of unit tid
            float gA = g4.x + (float)gc0;
            float gB = g4.y + (float)gc1;
            float gC = g4.z + (float)gc2;
            float gD = g4.w + (float)gc3;
            float aa = fast_tanh(gA);
            float ii = fast_sigmoid(gB);
            float ff = fast_sigmoid(gC);
            float oo = fast_sigmoid(gD);
            s = aa * ii + s * ff;
            float h = fast_tanh(s) * oo;
            out[((size_t)t * BATCH + b) * HID + tid] = h;
            hbuf[tid] = (_Float16)h;
            gc0 = gn0; gc1 = gn1; gc2 = gn2; gc3 = gn3;
        }
        __syncthreads();   // hbuf ready for next step's A-fragments
    }
}

extern "C" void kernel_launch(void* const* d_in, const int* in_sizes, int n_in,
                              void* d_out, int out_size, void* d_ws, size_t ws_size,
                              hipStream_t stream) {
    const float* X   = (const float*)d_in[0];
    const float* Wax = (const float*)d_in[1];
    const float* Wix = (const float*)d_in[2];
    const float* Wfx = (const float*)d_in[3];
    const float* Wox = (const float*)d_in[4];
    const float* Wah = (const float*)d_in[5];
    const float* Wih = (const float*)d_in[6];
    const float* Wfh = (const float*)d_in[7];
    const float* Woh = (const float*)d_in[8];
    const float* ba  = (const float*)d_in[9];
    const float* bi  = (const float*)d_in[10];
    const float* bf  = (const float*)d_in[11];
    const float* bo  = (const float*)d_in[12];

    _Float16* ws  = (_Float16*)d_ws;
    _Float16* Xh  = ws + XH_OFF;
    _Float16* Wxt = ws + WXT_OFF;
    _Float16* Wh2 = ws + WH2_OFF;
    _Float16* gxp = ws + GX_OFF;

    k_prep_x<<<dim3(GM * 256 / 4 / 256), dim3(256), 0, stream>>>(X, Xh);
    k_prep_w<<<dim3(1024), dim3(256), 0, stream>>>(Wax, Wix, Wfx, Wox, Wxt);
    k_prep_wfrag<<<dim3(128), dim3(256), 0, stream>>>(Wah, Wih, Wfh, Woh, Wh2);
    k_gemm<<<dim3(GM / 128, G4 / 64), dim3(256), 0, stream>>>(
        Xh, Wxt, ba, bi, bf, bo, gxp);
    k_recur<<<dim3(BATCH), dim3(256), 0, stream>>>(Wh2, gxp, (float*)d_out);
}